// Round 20
// baseline (201.143 us; speedup 1.0000x reference)
//
#include <hip/hip_runtime.h>
#include <hip/hip_bf16.h>
#include <stdint.h>

// B=4, T=4096, K=256, D=1024, H=16, hd=64
#define D_DIM 1024

using f32x4  = __attribute__((ext_vector_type(4))) float;
using short8 = __attribute__((ext_vector_type(8))) short;

__device__ __forceinline__ float bf2f(unsigned short u) {
    union { unsigned int i; float f; } v; v.i = ((unsigned int)u) << 16; return v.f;
}
__device__ __forceinline__ unsigned short f2bf(float f) {
    union { float f; unsigned int i; } v; v.f = f;
    unsigned int x = v.i;
    return (unsigned short)((x + 0x7fffu + ((x >> 16) & 1u)) >> 16);  // RNE
}
__device__ __forceinline__ void gload16(const void* g, void* l) {
    __builtin_amdgcn_global_load_lds(
        (const __attribute__((address_space(1))) void*)g,
        (__attribute__((address_space(3))) void*)l, 16, 0, 0);
}

// ---------------------------------------------------------------------------
// prep: fused {convw | transq | rms_split(ctx) | bounds}. (r19-validated)
// ---------------------------------------------------------------------------
__global__ __launch_bounds__(256)
void prep_kernel(const float* __restrict__ Wk, const float* __restrict__ Wv,
                 const float* __restrict__ Wo, const float* __restrict__ Wq,
                 const float* __restrict__ gkv, const float* __restrict__ gq,
                 const float* __restrict__ ctx, const int* __restrict__ cidx,
                 unsigned short* __restrict__ wk_hi, unsigned short* __restrict__ wk_lo,
                 unsigned short* __restrict__ wv_hi, unsigned short* __restrict__ wv_lo,
                 unsigned short* __restrict__ wo_b,
                 unsigned short* __restrict__ wqT_hi, unsigned short* __restrict__ wqT_lo,
                 unsigned short* __restrict__ ch, unsigned short* __restrict__ cl,
                 int2* __restrict__ bounds)
{
    __shared__ float tile[64][65];
    const int blk = blockIdx.x;
    const int tid = threadIdx.x;

    if (blk < 3072) {
        const int e   = (blk * 256 + tid) * 4;
        const int sel = e >> 20;
        const int off = e & 0xFFFFF;
        const float* src = sel == 0 ? Wk : sel == 1 ? Wv : Wo;
        float4 v = *(const float4*)(src + off);
        if (sel < 2) {
            float4 g = *(const float4*)(gkv + (off & 1023));
            v.x *= g.x; v.y *= g.y; v.z *= g.z; v.w *= g.w;
            ushort4 h, l;
            h.x = f2bf(v.x); l.x = f2bf(v.x - bf2f(h.x));
            h.y = f2bf(v.y); l.y = f2bf(v.y - bf2f(h.y));
            h.z = f2bf(v.z); l.z = f2bf(v.z - bf2f(h.z));
            h.w = f2bf(v.w); l.w = f2bf(v.w - bf2f(h.w));
            unsigned short* hi = sel == 0 ? wk_hi : wv_hi;
            unsigned short* lo = sel == 0 ? wk_lo : wv_lo;
            *(ushort4*)(hi + off) = h;
            *(ushort4*)(lo + off) = l;
        } else {
            ushort4 o;
            o.x = f2bf(v.x); o.y = f2bf(v.y); o.z = f2bf(v.z); o.w = f2bf(v.w);
            *(ushort4*)(wo_b + off) = o;
        }
    } else if (blk < 3328) {
        const int bb = blk - 3072;
        const int c0 = (bb & 15) * 64;
        const int i0 = (bb >> 4) * 64;
#pragma unroll
        for (int j = 0; j < 4; ++j) {
            const int e  = tid + j * 256;
            const int rl = e >> 4;
            const int q4 = e & 15;
            float4 v = *(const float4*)(Wq + (long)(c0 + rl) * 1024 + i0 + q4 * 4);
            tile[q4 * 4 + 0][rl] = v.x;
            tile[q4 * 4 + 1][rl] = v.y;
            tile[q4 * 4 + 2][rl] = v.z;
            tile[q4 * 4 + 3][rl] = v.w;
        }
        __syncthreads();
#pragma unroll
        for (int j = 0; j < 4; ++j) {
            const int e  = tid + j * 256;
            const int il = e >> 4;
            const int s4 = e & 15;
            const float g = gq[i0 + il];
            float v0 = tile[il][s4 * 4 + 0] * g;
            float v1 = tile[il][s4 * 4 + 1] * g;
            float v2 = tile[il][s4 * 4 + 2] * g;
            float v3 = tile[il][s4 * 4 + 3] * g;
            ushort4 hh, ll;
            hh.x = f2bf(v0); ll.x = f2bf(v0 - bf2f(hh.x));
            hh.y = f2bf(v1); ll.y = f2bf(v1 - bf2f(hh.y));
            hh.z = f2bf(v2); ll.z = f2bf(v2 - bf2f(hh.z));
            hh.w = f2bf(v3); ll.w = f2bf(v3 - bf2f(hh.w));
            const long o = (long)(i0 + il) * 1024 + c0 + s4 * 4;
            *(ushort4*)(wqT_hi + o) = hh;
            *(ushort4*)(wqT_lo + o) = ll;
        }
    } else if (blk < 4352) {
        const long row = blk - 3328;
        float4 v = ((const float4*)(ctx + row * D_DIM))[tid];
        float ss = v.x*v.x + v.y*v.y + v.z*v.z + v.w*v.w;
#pragma unroll
        for (int m = 32; m; m >>= 1) ss += __shfl_xor(ss, m);
        float* red = &tile[0][0];
        if ((tid & 63) == 0) red[tid >> 6] = ss;
        __syncthreads();
        const float tot = red[0] + red[1] + red[2] + red[3];
        const float scale = rsqrtf(tot * (1.0f / 1024.0f) + 1.1920929e-07f);
        v.x *= scale; v.y *= scale; v.z *= scale; v.w *= scale;
        ushort4 h, l;
        h.x = f2bf(v.x); l.x = f2bf(v.x - bf2f(h.x));
        h.y = f2bf(v.y); l.y = f2bf(v.y - bf2f(h.y));
        h.z = f2bf(v.z); l.z = f2bf(v.z - bf2f(h.z));
        h.w = f2bf(v.w); l.w = f2bf(v.w - bf2f(h.w));
        *(ushort4*)(ch + row * D_DIM + tid * 4) = h;
        *(ushort4*)(cl + row * D_DIM + tid * 4) = l;
    } else {
        const int b = blk - 4352;
        const int p = tid;
        const int* ci = cidx + (b << 12);
        int l = 0, r = 4096;
        while (l < r) { int m = (l + r) >> 1; if (ci[m] < p - 1) l = m + 1; else r = m; }
        const int lo = l;
        r = 4096;
        while (l < r) { int m = (l + r) >> 1; if (ci[m] <= p + 1) l = m + 1; else r = m; }
        bounds[(b << 8) + p] = make_int2(lo, l);
    }
}

// ---------------------------------------------------------------------------
// gemm_kv: z=0: k split-precision -> kh/kl bf16. z=1: v ~= ch@Wv'_hi^T -> f32.
// ---------------------------------------------------------------------------
__global__ __launch_bounds__(256)
void gemm_kv(const unsigned short* __restrict__ ch, const unsigned short* __restrict__ cl,
             const unsigned short* __restrict__ wkh, const unsigned short* __restrict__ wkl,
             const unsigned short* __restrict__ wvh,
             unsigned short* __restrict__ kh, unsigned short* __restrict__ kl,
             float* __restrict__ v_f)
{
    __shared__ unsigned short Ah[4096], Al[4096], Bh[4096], Bl[4096];
    const bool full = (blockIdx.z == 0);
    const unsigned short* Bhp = full ? wkh : wvh;
    const unsigned short* Blp = wkl;

    const int tid = threadIdx.x, lane = tid & 63, wave = tid >> 6;
    const int wm = wave >> 1, wn = wave & 1;
    const long Arow0 = (long)blockIdx.y * 128;
    const int  Brow0 = blockIdx.x * 128;
    const int fr = lane & 15, ks = lane >> 4;
    const int ksz = (ks ^ ((fr >> 1) & 3)) << 4;
    const int kq  = ((tid & 3) ^ ((tid >> 3) & 3)) * 8;
    const int srow = tid >> 2;

    const long a_off0 = (Arow0 + srow) * D_DIM + kq;
    const long a_off1 = (Arow0 + srow + 64) * D_DIM + kq;
    const long b_off0 = (long)(Brow0 + srow) * D_DIM + kq;
    const long b_off1 = (long)(Brow0 + srow + 64) * D_DIM + kq;

    f32x4 acc[4][4] = {};
    char* AhB = (char*)Ah; char* AlB = (char*)Al;
    char* BhB = (char*)Bh; char* BlB = (char*)Bl;

    for (int kt = 0; kt < 32; ++kt) {
        const int k0 = kt * 32;
        gload16(ch + a_off0 + k0, AhB + tid * 16);
        gload16(ch + a_off1 + k0, AhB + 4096 + tid * 16);
        gload16(Bhp + b_off0 + k0, BhB + tid * 16);
        gload16(Bhp + b_off1 + k0, BhB + 4096 + tid * 16);
        if (full) {
            gload16(cl + a_off0 + k0, AlB + tid * 16);
            gload16(cl + a_off1 + k0, AlB + 4096 + tid * 16);
            gload16(Blp + b_off0 + k0, BlB + tid * 16);
            gload16(Blp + b_off1 + k0, BlB + 4096 + tid * 16);
        }
        __syncthreads();

        short8 ah[4], al[4], bh[4], bl[4];
#pragma unroll
        for (int mi = 0; mi < 4; ++mi) {
            const int aoff = (wm * 64 + mi * 16 + fr) * 64 + ksz;
            ah[mi] = *(const short8*)(AhB + aoff);
            if (full) al[mi] = *(const short8*)(AlB + aoff);
        }
#pragma unroll
        for (int ni = 0; ni < 4; ++ni) {
            const int boff = (wn * 64 + ni * 16 + fr) * 64 + ksz;
            bh[ni] = *(const short8*)(BhB + boff);
            if (full) bl[ni] = *(const short8*)(BlB + boff);
        }
#pragma unroll
        for (int mi = 0; mi < 4; ++mi)
#pragma unroll
            for (int ni = 0; ni < 4; ++ni) {
                acc[mi][ni] = __builtin_amdgcn_mfma_f32_16x16x32_bf16(ah[mi], bh[ni], acc[mi][ni], 0, 0, 0);
                if (full) {
                    acc[mi][ni] = __builtin_amdgcn_mfma_f32_16x16x32_bf16(al[mi], bh[ni], acc[mi][ni], 0, 0, 0);
                    acc[mi][ni] = __builtin_amdgcn_mfma_f32_16x16x32_bf16(ah[mi], bl[ni], acc[mi][ni], 0, 0, 0);
                }
            }
        __syncthreads();
    }

    const int c = lane & 15, r0 = (lane >> 4) * 4;
#pragma unroll
    for (int mi = 0; mi < 4; ++mi)
#pragma unroll
        for (int ni = 0; ni < 4; ++ni)
#pragma unroll
            for (int j = 0; j < 4; ++j) {
                const long row = Arow0 + wm * 64 + mi * 16 + r0 + j;
                const int  col = Brow0 + wn * 64 + ni * 16 + c;
                const float val = acc[mi][ni][j];
                if (full) {
                    const unsigned short hh = f2bf(val);
                    kh[row * D_DIM + col] = hh;
                    kl[row * D_DIM + col] = f2bf(val - bf2f(hh));
                } else {
                    v_f[row * D_DIM + col] = val;
                }
            }
}

// ---------------------------------------------------------------------------
// gemm_U: U[b,p,h][i] = sum_d (kh+kl)[(b,p),h*64+d]*(wqT_h+l)[i,h*64+d],
// epilogue -> bf16 hi/lo (Uh/Ul).
// ---------------------------------------------------------------------------
__global__ __launch_bounds__(256)
void gemm_U(const unsigned short* __restrict__ kh, const unsigned short* __restrict__ kl,
            const unsigned short* __restrict__ th, const unsigned short* __restrict__ tl,
            unsigned short* __restrict__ Uh, unsigned short* __restrict__ Ul)
{
    __shared__ unsigned short Ah[4096], Al[4096], Bh[4096], Bl[4096];
    const int h = blockIdx.z;
    const int tid = threadIdx.x, lane = tid & 63, wave = tid >> 6;
    const int wm = wave >> 1, wn = wave & 1;
    const long Arow0 = (long)blockIdx.y * 128;
    const int  Brow0 = blockIdx.x * 128;
    const int fr = lane & 15, ks = lane >> 4;
    const int ksz = (ks ^ ((fr >> 1) & 3)) << 4;
    const int kq  = ((tid & 3) ^ ((tid >> 3) & 3)) * 8;
    const int srow = tid >> 2;
    const int kb = h * 64;

    const long a_off0 = (Arow0 + srow) * D_DIM + kb + kq;
    const long a_off1 = (Arow0 + srow + 64) * D_DIM + kb + kq;
    const long b_off0 = (long)(Brow0 + srow) * D_DIM + kb + kq;
    const long b_off1 = (long)(Brow0 + srow + 64) * D_DIM + kb + kq;

    f32x4 acc[4][4] = {};
    char* AhB = (char*)Ah; char* AlB = (char*)Al;
    char* BhB = (char*)Bh; char* BlB = (char*)Bl;

    for (int kt = 0; kt < 2; ++kt) {
        const int k0 = kt * 32;
        gload16(kh + a_off0 + k0, AhB + tid * 16);
        gload16(kh + a_off1 + k0, AhB + 4096 + tid * 16);
        gload16(kl + a_off0 + k0, AlB + tid * 16);
        gload16(kl + a_off1 + k0, AlB + 4096 + tid * 16);
        gload16(th + b_off0 + k0, BhB + tid * 16);
        gload16(th + b_off1 + k0, BhB + 4096 + tid * 16);
        gload16(tl + b_off0 + k0, BlB + tid * 16);
        gload16(tl + b_off1 + k0, BlB + 4096 + tid * 16);
        __syncthreads();

        short8 ah[4], al[4], bh[4], bl[4];
#pragma unroll
        for (int mi = 0; mi < 4; ++mi) {
            const int aoff = (wm * 64 + mi * 16 + fr) * 64 + ksz;
            ah[mi] = *(const short8*)(AhB + aoff);
            al[mi] = *(const short8*)(AlB + aoff);
        }
#pragma unroll
        for (int ni = 0; ni < 4; ++ni) {
            const int boff = (wn * 64 + ni * 16 + fr) * 64 + ksz;
            bh[ni] = *(const short8*)(BhB + boff);
            bl[ni] = *(const short8*)(BlB + boff);
        }
#pragma unroll
        for (int mi = 0; mi < 4; ++mi)
#pragma unroll
            for (int ni = 0; ni < 4; ++ni) {
                acc[mi][ni] = __builtin_amdgcn_mfma_f32_16x16x32_bf16(ah[mi], bh[ni], acc[mi][ni], 0, 0, 0);
                acc[mi][ni] = __builtin_amdgcn_mfma_f32_16x16x32_bf16(al[mi], bh[ni], acc[mi][ni], 0, 0, 0);
                acc[mi][ni] = __builtin_amdgcn_mfma_f32_16x16x32_bf16(ah[mi], bl[ni], acc[mi][ni], 0, 0, 0);
            }
        __syncthreads();
    }

    const int c = lane & 15, r0 = (lane >> 4) * 4;
#pragma unroll
    for (int mi = 0; mi < 4; ++mi)
#pragma unroll
        for (int ni = 0; ni < 4; ++ni)
#pragma unroll
            for (int j = 0; j < 4; ++j) {
                const long row = Arow0 + wm * 64 + mi * 16 + r0 + j;
                const int  col = Brow0 + wn * 64 + ni * 16 + c;
                const float val = acc[mi][ni][j];
                const long o = ((long)row * 16 + h) * 1024 + col;
                const unsigned short hh = f2bf(val);
                Uh[o] = hh;
                Ul[o] = f2bf(val - bf2f(hh));
            }
}

// ---------------------------------------------------------------------------
// score v7 (r18/r19-validated): 2-way K-split + precomputed bounds.
// ---------------------------------------------------------------------------
__global__ __launch_bounds__(256)
void score_gemm(const float* __restrict__ x, const int* __restrict__ cidx,
                const int2* __restrict__ bounds,
                const unsigned short* __restrict__ Uh, const unsigned short* __restrict__ Ul,
                float* __restrict__ sbuf, float* __restrict__ ssbuf)
{
    const int pg = blockIdx.x;
    const int mh = blockIdx.y;
    const int bz = blockIdx.z;
    const int b  = bz & 3;
    const int ksp = bz >> 2;
    const int kbase = ksp << 9;
    const int p0 = pg * 4;
    const int lo = bounds[(b << 8) + p0].x;
    const int hi = bounds[(b << 8) + p0 + 3].y;
    if (lo + mh * 64 >= hi) return;
    const int* ci = cidx + (b << 12);

    float* const sb = sbuf + (long)ksp * 786432;
    float* const ssb = ssbuf + (ksp << 14);

    __shared__ unsigned short AhS[2][2048], AlS[2][2048];
    __shared__ unsigned short UhS[2][2048], UlS[2][2048];

    const int tid = threadIdx.x, lane = tid & 63, wave = tid >> 6;
    const int fr = lane & 15;
    const int ks = lane >> 4;
    const int ksz = (ks ^ ((fr >> 1) & 3)) << 4;

    const int arow = tid >> 2, aq = tid & 3;
    const int aslot = aq ^ ((arow >> 1) & 3);
    const unsigned short* const Uhb = Uh + ((long)((b << 8) + p0) * 16) * 1024 + kbase;
    const unsigned short* const Ulb = Ul + ((long)((b << 8) + p0) * 16) * 1024 + kbase;
    const float* const xb = x + ((long)b << 12) * 1024 + kbase;

    for (int t0 = lo + mh * 64; t0 < hi; t0 += 128) {
        const int tc0 = (t0 + arow < hi) ? (t0 + arow) : (hi - 1);
        const float* xr = xb + (long)tc0 * 1024 + aq * 8;
        float ss = 0.f;

        gload16(Uhb + (long)arow * 1024 + aslot * 8, (char*)&UhS[0][0] + tid * 16);
        gload16(Ulb + (long)arow * 1024 + aslot * 8, (char*)&UlS[0][0] + tid * 16);
        {
            const float4 v0 = *(const float4*)(xr);
            const float4 v1 = *(const float4*)(xr + 4);
            ss += v0.x*v0.x + v0.y*v0.y + v0.z*v0.z + v0.w*v0.w
                + v1.x*v1.x + v1.y*v1.y + v1.z*v1.z + v1.w*v1.w;
            short8 hv, lv;
            unsigned short h_;
            h_ = f2bf(v0.x); hv[0] = (short)h_; lv[0] = (short)f2bf(v0.x - bf2f(h_));
            h_ = f2bf(v0.y); hv[1] = (short)h_; lv[1] = (short)f2bf(v0.y - bf2f(h_));
            h_ = f2bf(v0.z); hv[2] = (short)h_; lv[2] = (short)f2bf(v0.z - bf2f(h_));
            h_ = f2bf(v0.w); hv[3] = (short)h_; lv[3] = (short)f2bf(v0.w - bf2f(h_));
            h_ = f2bf(v1.x); hv[4] = (short)h_; lv[4] = (short)f2bf(v1.x - bf2f(h_));
            h_ = f2bf(v1.y); hv[5] = (short)h_; lv[5] = (short)f2bf(v1.y - bf2f(h_));
            h_ = f2bf(v1.z); hv[6] = (short)h_; lv[6] = (short)f2bf(v1.z - bf2f(h_));
            h_ = f2bf(v1.w); hv[7] = (short)h_; lv[7] = (short)f2bf(v1.w - bf2f(h_));
            *(short8*)((char*)&AhS[0][0] + arow * 64 + aslot * 16) = hv;
            *(short8*)((char*)&AlS[0][0] + arow * 64 + aslot * 16) = lv;
        }
        __syncthreads();

        f32x4 acc[4] = {};
        for (int t = 0; t < 16; ++t) {
            const int cur = t & 1, nxt = cur ^ 1;
            float4 v0, v1;
            if (t < 15) {
                const int k0n = (t + 1) * 32;
                gload16(Uhb + (long)arow * 1024 + k0n + aslot * 8, (char*)&UhS[nxt][0] + tid * 16);
                gload16(Ulb + (long)arow * 1024 + k0n + aslot * 8, (char*)&UlS[nxt][0] + tid * 16);
                v0 = *(const float4*)(xr + k0n);
                v1 = *(const float4*)(xr + k0n + 4);
            }

            const int aoff = cur * 4096 + (wave * 16 + fr) * 64 + ksz;
            const short8 ah = *(const short8*)((char*)&AhS[0][0] + aoff);
            const short8 al = *(const short8*)((char*)&AlS[0][0] + aoff);
#pragma unroll
            for (int ni = 0; ni < 4; ++ni) {
                const int boff = cur * 4096 + (ni * 16 + fr) * 64 + ksz;
                const short8 uh = *(const short8*)((char*)&UhS[0][0] + boff);
                const short8 ul = *(const short8*)((char*)&UlS[0][0] + boff);
                acc[ni] = __builtin_amdgcn_mfma_f32_16x16x32_bf16(ah, uh, acc[ni], 0, 0, 0);
                acc[ni] = __builtin_amdgcn_mfma_f32_16x16x32_bf16(al, uh, acc[ni], 0, 0, 0);
                acc[ni] = __builtin_amdgcn_mfma_f32_16x16x32_bf16(ah, ul, acc[ni], 0, 0, 0);
            }

            if (t < 15) {
                ss += v0.x*v0.x + v0.y*v0.y + v0.z*v0.z + v0.w*v0.w
                    + v1.x*v1.x + v1.y*v1.y + v1.z*v1.z + v1.w*v1.w;
                short8 hv, lv;
                unsigned short h_;
                h_ = f2bf(v0.x); hv[0] = (short)h_; lv[0] = (short)f2bf(v0.x - bf2f(h_));
                h_ = f2bf(v0.y); hv[1] = (short)h_; lv[1] = (short)f2bf(v0.y - bf2f(h_));
                h_ = f2bf(v0.z); hv[2] = (short)h_; lv[2] = (short)f2bf(v0.z - bf2f(h_));
                h_ = f2bf(v0.w); hv[3] = (short)h_; lv[3] = (short)f2bf(v0.w - bf2f(h_));
                h_ = f2bf(v1.x); hv[4] = (short)h_; lv[4] = (short)f2bf(v1.x - bf2f(h_));
                h_ = f2bf(v1.y); hv[5] = (short)h_; lv[5] = (short)f2bf(v1.y - bf2f(h_));
                h_ = f2bf(v1.z); hv[6] = (short)h_; lv[6] = (short)f2bf(v1.z - bf2f(h_));
                h_ = f2bf(v1.w); hv[7] = (short)h_; lv[7] = (short)f2bf(v1.w - bf2f(h_));
                *(short8*)((char*)&AhS[0][0] + nxt * 4096 + arow * 64 + aslot * 16) = hv;
                *(short8*)((char*)&AlS[0][0] + nxt * 4096 + arow * 64 + aslot * 16) = lv;
            }
            __syncthreads();
        }

        ss += __shfl_xor(ss, 1);
        ss += __shfl_xor(ss, 2);
        if (aq == 0 && t0 + arow < hi)
            ssb[(b << 12) + t0 + arow] = ss;

        const int hcol = lane & 15;
        const int r0j = (lane >> 4) * 4;
#pragma unroll
        for (int j = 0; j < 4; ++j) {
            const int trow = t0 + wave * 16 + r0j + j;
            if (trow < hi) {
                const long tg = ((long)b << 12) + trow;
                const int idx = ci[trow];
#pragma unroll
                for (int ni = 0; ni < 4; ++ni) {
                    const int dp = p0 + ni - idx + 1;
                    if (dp >= 0 && dp <= 2)
                        sb[(tg * 16 + hcol) * 3 + dp] = acc[ni][j];
                }
            }
        }
        __syncthreads();
    }
}

// ---------------------------------------------------------------------------
// attnout: dot = sum of K-halves; s = dot*rsqrt(mean xx+eps)/8; w=relu(s)^2,
// normalize, out = sum w*v. ao bf16.
// ---------------------------------------------------------------------------
__global__ __launch_bounds__(256)
void attnout_kernel(const float* __restrict__ sbuf, const float* __restrict__ ssbuf,
                    const float* __restrict__ vf, const int* __restrict__ cidx,
                    unsigned short* __restrict__ ao)
{
    const int tid = threadIdx.x;
    const int tg = tid >> 4, h = tid & 15;
    const int t = blockIdx.x * 16 + tg;
    const int b = t >> 12;
    const int idx = cidx[t];
    const float* sb0 = sbuf + ((long)t * 16 + h) * 3;
    const float* sb1 = sb0 + 786432;
    const float ssum = ssbuf[t] + ssbuf[t + 16384];
    const float scale = rsqrtf(ssum * (1.0f / 1024.0f) + 1.1920929e-07f) * 0.125f;
    float w0 = 0.f, w1 = 0.f, w2 = 0.f, wsum = 0.f;
    if (idx - 1 >= 0) { float s = (sb0[0] + sb1[0]) * scale; if (s > 0.f) { w0 = s * s; wsum += w0; } }
    { float s = (sb0[1] + sb1[1]) * scale; if (s > 0.f) { w1 = s * s; wsum += w1; } }
    if (idx + 1 < 256) { float s = (sb0[2] + sb1[2]) * scale; if (s > 0.f) { w2 = s * s; wsum += w2; } }
    const float inv = 1.0f / fmaxf(wsum, 1e-6f);
    w0 *= inv; w1 *= inv; w2 *= inv;
    const int p0 = idx > 0 ? idx - 1 : 0;
    const int p2 = idx < 255 ? idx + 1 : 255;
    const float4* v0 = (const float4*)(vf + ((long)(b * 256 + p0)) * 1024 + h * 64);
    const float4* v1 = (const float4*)(vf + ((long)(b * 256 + idx)) * 1024 + h * 64);
    const float4* v2 = (const float4*)(vf + ((long)(b * 256 + p2)) * 1024 + h * 64);
    ushort4* aop = (ushort4*)(ao + (long)t * 1024 + h * 64);
#pragma unroll
    for (int q = 0; q < 16; ++q) {
        float4 a0 = v0[q], a1 = v1[q], a2 = v2[q];
        ushort4 o;
        o.x = f2bf(w0 * a0.x + w1 * a1.x + w2 * a2.x);
        o.y = f2bf(w0 * a0.y + w1 * a1.y + w2 * a2.y);
        o.z = f2bf(w0 * a0.z + w1 * a1.z + w2 * a2.z);
        o.w = f2bf(w0 * a0.w + w1 * a1.w + w2 * a2.w);
        aop[q] = o;
    }
}

// ---------------------------------------------------------------------------
// out = x + ao @ Wo^T, 128x128 tiles, swizzled, 8-PHASE deep-pipelined
// (r15 schedule ported; identical per-stage load counts -> same vmcnt math).
// 256 thr / 4 waves (2x2, wave=64x64). LDS 4 regions x (8KB A + 8KB B) =
// 64KB -> 2 blocks/CU resident; grid 1024 (4 gens/CU) so epilogue HBM
// (resid read + f32 write) overlaps successor blocks' K-loops.
// XCD decode: bx = lin&7 (one Wo col-panel per XCD, L2-resident).
// ---------------------------------------------------------------------------
__global__ __launch_bounds__(256, 2)
void gemm_out128(const unsigned short* __restrict__ A,
                 const unsigned short* __restrict__ W,
                 float* __restrict__ C, const float* __restrict__ resid)
{
    __shared__ unsigned short As[4][4096];
    __shared__ unsigned short Bs[4][4096];

    const int lin = blockIdx.x;
    const int bx = lin & 7;            // col-block (0..7) -> one per XCD
    const int by = lin >> 3;           // row-block (0..127)
    const long row0 = (long)by * 128;
    const int  col0 = bx * 128;

    const int tid = threadIdx.x, lane = tid & 63, wave = tid >> 6;
    const int wm = wave >> 1, wn = wave & 1;
    const int fr = lane & 15, ks = lane >> 4;
    const int ksz = (ks ^ ((fr >> 1) & 3)) << 4;
    const int kq  = ((tid & 3) ^ ((tid >> 3) & 3)) * 8;
    const int srow = tid >> 2;

    const long a_off0 = (row0 + srow) * D_DIM + kq;
    const long a_off1 = (row0 + 64 + srow) * D_DIM + kq;
    const long b_off0 = (long)(col0 + srow) * D_DIM + kq;
    const long b_off1 = (long)(col0 + 64 + srow) * D_DIM + kq;

    f32x4 acc[4][4] = {};

#define STAGE_A(X) do { const int kofs_ = (X) * 32;                          \
    char* base_ = (char*)&As[(X) & 3][0];                                    \
    gload16(A + a_off0 + kofs_, base_ + tid * 16);                           \
    gload16(A + a_off1 + kofs_, base_ + 4096 + tid * 16); } while (0)
#define STAGE_B(X) do { const int kofs_ = (X) * 32;                          \
    char* base_ = (char*)&Bs[(X) & 3][0];                                    \
    gload16(W + b_off0 + kofs_, base_ + tid * 16);                           \
    gload16(W + b_off1 + kofs_, base_ + 4096 + tid * 16); } while (0)

    // prologue: tiles 0,1,2 (FIFO); wait tiles 0,1 landed (tile 2 in flight)
    STAGE_A(0); STAGE_B(0); STAGE_A(1); STAGE_B(1); STAGE_A(2); STAGE_B(2);
    asm volatile("s_waitcnt vmcnt(4)" ::: "memory");
    __builtin_amdgcn_s_barrier();
    __builtin_amdgcn_sched_barrier(0);

    short8 bfrag[4];

    for (int i = 0; i < 8; ++i) {
        const int Tb = i * 4;
        const bool last = (i == 7);
#pragma unroll
        for (int ph = 0; ph < 8; ++ph) {
            const int tp = ph >> 1;            // tile within iter (0..3)
            const int h  = ph & 1;             // mi-half (mi 0,1 vs 2,3)
            const int rg = tp;                 // region = (Tb+tp)&3 = tp
            if (h == 0) {
#pragma unroll
                for (int ni = 0; ni < 4; ++ni)
                    bfrag[ni] = *(const short8*)((char*)&Bs[rg][0] +
                                (wn * 64 + ni * 16 + fr) * 64 + ksz);
            }
            short8 afrag[2];
#pragma unroll
            for (int mi = 0; mi < 2; ++mi)
                afrag[mi] = *(const short8*)((char*)&As[rg][0] +
                            (wm * 64 + (h * 2 + mi) * 16 + fr) * 64 + ksz);
            {
                const int SX = Tb + 3 + tp;
                if (SX < 32) {
                    if (h == 0) STAGE_A(SX); else STAGE_B(SX);
                }
            }
            if (ph == 3) {
                if (last) asm volatile("s_waitcnt vmcnt(0)" ::: "memory");
                else      asm volatile("s_waitcnt vmcnt(4)" ::: "memory");
            } else if (ph == 7) {
                if (!last) asm volatile("s_waitcnt vmcnt(4)" ::: "memory");
            }
            __builtin_amdgcn_s_barrier();
            asm volatile("s_waitcnt lgkmcnt(0)" ::: "memory");
            __builtin_amdgcn_sched_barrier(0);
            __builtin_amdgcn_s_setprio(1);
#pragma unroll
            for (int mi = 0; mi < 2; ++mi)
#pragma unroll
                for (int ni = 0; ni < 4; ++ni)
                    acc[h * 2 + mi][ni] = __builtin_amdgcn_mfma_f32_16x16x32_bf16(
                        afrag[mi], bfrag[ni], acc[h * 2 + mi][ni], 0, 0, 0);
            __builtin_amdgcn_s_setprio(0);
            __builtin_amdgcn_sched_barrier(0);
            __builtin_amdgcn_s_barrier();
            __builtin_amdgcn_sched_barrier(0);
        }
    }
#undef STAGE_A
#undef STAGE_B

    const int c = lane & 15, rg2 = lane >> 4;
#pragma unroll
    for (int mi = 0; mi < 4; ++mi)
#pragma unroll
        for (int ni = 0; ni < 4; ++ni)
#pragma unroll
            for (int j = 0; j < 4; ++j) {
                const long row = row0 + wm * 64 + mi * 16 + rg2 * 4 + j;
                const int  col = col0 + wn * 64 + ni * 16 + c;
                C[row * D_DIM + col] = resid[row * D_DIM + col] + acc[mi][ni][j];
            }
}

// ---------------------------------------------------------------------------
extern "C" void kernel_launch(void* const* d_in, const int* in_sizes, int n_in,
                              void* d_out, int out_size, void* d_ws, size_t ws_size,
                              hipStream_t stream)
{
    const float* x    = (const float*)d_in[0];
    const float* ctx  = (const float*)d_in[1];
    const int*   cidx = (const int*)d_in[2];
    const float* gq   = (const float*)d_in[3];
    const float* gkv  = (const float*)d_in[4];
    const float* Wq   = (const float*)d_in[5];
    const float* Wk   = (const float*)d_in[6];
    const float* Wv   = (const float*)d_in[7];
    const float* Wo   = (const float*)d_in[8];
    float* out = (float*)d_out;

    char* ws = (char*)d_ws;
    const size_t MB = 1 << 20;
    unsigned short* wqT_hi = (unsigned short*)(ws + 0 * MB);
    unsigned short* wqT_lo = (unsigned short*)(ws + 2 * MB);
    unsigned short* wk_hi  = (unsigned short*)(ws + 4 * MB);
    unsigned short* wk_lo  = (unsigned short*)(ws + 6 * MB);
    unsigned short* wv_hi  = (unsigned short*)(ws + 8 * MB);
    unsigned short* wv_lo  = (unsigned short*)(ws + 10 * MB);
    unsigned short* wo_b   = (unsigned short*)(ws + 12 * MB);
    unsigned short* ch = (unsigned short*)(ws + 14 * MB);
    unsigned short* cl = (unsigned short*)(ws + 16 * MB);
    unsigned short* kh = (unsigned short*)(ws + 18 * MB);
    unsigned short* kl = (unsigned short*)(ws + 20 * MB);
    float* v_f = (float*)(ws + 22 * MB);                      // 4MB
    unsigned short* Uh = (unsigned short*)(ws + 26 * MB);     // 32MB (26..58)
    unsigned short* Ul = (unsigned short*)(ws + 58 * MB);     // 32MB (58..90)
    unsigned short* ao_b = (unsigned short*)(ws + 26 * MB);   // 32MB, ALIASES Uh
        // (Uh dead after score_gemm; attnout writes ao afterwards)
    float* sbuf  = (float*)(ws + 91 * MB);                    // 2 x 3MB (91..97)
    float* ssbuf = (float*)(ws + 97 * MB);                    // 2 x 64KB
    int2*  bounds = (int2*)(ws + 98 * MB);                    // 8KB; total ~98MB

    // 1. fused preprocessing: convw | transq | rms_split(ctx) | bounds
    prep_kernel<<<4356, 256, 0, stream>>>(Wk, Wv, Wo, Wq, gkv, gq, ctx, cidx,
                                          wk_hi, wk_lo, wv_hi, wv_lo, wo_b,
                                          wqT_hi, wqT_lo, ch, cl, bounds);
    // 2. k (split bf16), v (f32)
    gemm_kv<<<dim3(8, 8, 2), 256, 0, stream>>>(ch, cl, wk_hi, wk_lo, wv_hi,
                                               kh, kl, v_f);
    // 3. U = per-head Wq'^T k, bf16 hi/lo
    gemm_U<<<dim3(8, 8, 16), 256, 0, stream>>>(kh, kl, wqT_hi, wqT_lo, Uh, Ul);
    // 4. band scores (2-way K-split, precomputed bounds)
    score_gemm<<<dim3(64, 2, 8), 256, 0, stream>>>(x, cidx, bounds, Uh, Ul,
                                                   sbuf, ssbuf);
    // 5. normalize + weighted V -> ao
    attnout_kernel<<<1024, 256, 0, stream>>>(sbuf, ssbuf, v_f, cidx, ao_b);
    // 6. out = x + ao @ Wo^T (128x128 8-phase, 2 blocks/CU)
    gemm_out128<<<1024, 256, 0, stream>>>(ao_b, wo_b, out, x);
}

// Round 21
// 188.674 us; speedup vs baseline: 1.0661x; 1.0661x over previous
//
#include <hip/hip_runtime.h>
#include <hip/hip_bf16.h>
#include <stdint.h>

// B=4, T=4096, K=256, D=1024, H=16, hd=64
#define D_DIM 1024

using f32x4  = __attribute__((ext_vector_type(4))) float;
using short8 = __attribute__((ext_vector_type(8))) short;

__device__ __forceinline__ float bf2f(unsigned short u) {
    union { unsigned int i; float f; } v; v.i = ((unsigned int)u) << 16; return v.f;
}
__device__ __forceinline__ unsigned short f2bf(float f) {
    union { float f; unsigned int i; } v; v.f = f;
    unsigned int x = v.i;
    return (unsigned short)((x + 0x7fffu + ((x >> 16) & 1u)) >> 16);  // RNE
}
__device__ __forceinline__ void gload16(const void* g, void* l) {
    __builtin_amdgcn_global_load_lds(
        (const __attribute__((address_space(1))) void*)g,
        (__attribute__((address_space(3))) void*)l, 16, 0, 0);
}

// ---------------------------------------------------------------------------
// prep: fused {convw | transq | rms_split(ctx) | bounds}. (r19-validated)
// ---------------------------------------------------------------------------
__global__ __launch_bounds__(256)
void prep_kernel(const float* __restrict__ Wk, const float* __restrict__ Wv,
                 const float* __restrict__ Wo, const float* __restrict__ Wq,
                 const float* __restrict__ gkv, const float* __restrict__ gq,
                 const float* __restrict__ ctx, const int* __restrict__ cidx,
                 unsigned short* __restrict__ wk_hi, unsigned short* __restrict__ wk_lo,
                 unsigned short* __restrict__ wv_hi, unsigned short* __restrict__ wv_lo,
                 unsigned short* __restrict__ wo_b,
                 unsigned short* __restrict__ wqT_hi, unsigned short* __restrict__ wqT_lo,
                 unsigned short* __restrict__ ch, unsigned short* __restrict__ cl,
                 int2* __restrict__ bounds)
{
    __shared__ float tile[64][65];
    const int blk = blockIdx.x;
    const int tid = threadIdx.x;

    if (blk < 3072) {
        const int e   = (blk * 256 + tid) * 4;
        const int sel = e >> 20;
        const int off = e & 0xFFFFF;
        const float* src = sel == 0 ? Wk : sel == 1 ? Wv : Wo;
        float4 v = *(const float4*)(src + off);
        if (sel < 2) {
            float4 g = *(const float4*)(gkv + (off & 1023));
            v.x *= g.x; v.y *= g.y; v.z *= g.z; v.w *= g.w;
            ushort4 h, l;
            h.x = f2bf(v.x); l.x = f2bf(v.x - bf2f(h.x));
            h.y = f2bf(v.y); l.y = f2bf(v.y - bf2f(h.y));
            h.z = f2bf(v.z); l.z = f2bf(v.z - bf2f(h.z));
            h.w = f2bf(v.w); l.w = f2bf(v.w - bf2f(h.w));
            unsigned short* hi = sel == 0 ? wk_hi : wv_hi;
            unsigned short* lo = sel == 0 ? wk_lo : wv_lo;
            *(ushort4*)(hi + off) = h;
            *(ushort4*)(lo + off) = l;
        } else {
            ushort4 o;
            o.x = f2bf(v.x); o.y = f2bf(v.y); o.z = f2bf(v.z); o.w = f2bf(v.w);
            *(ushort4*)(wo_b + off) = o;
        }
    } else if (blk < 3328) {
        const int bb = blk - 3072;
        const int c0 = (bb & 15) * 64;
        const int i0 = (bb >> 4) * 64;
#pragma unroll
        for (int j = 0; j < 4; ++j) {
            const int e  = tid + j * 256;
            const int rl = e >> 4;
            const int q4 = e & 15;
            float4 v = *(const float4*)(Wq + (long)(c0 + rl) * 1024 + i0 + q4 * 4);
            tile[q4 * 4 + 0][rl] = v.x;
            tile[q4 * 4 + 1][rl] = v.y;
            tile[q4 * 4 + 2][rl] = v.z;
            tile[q4 * 4 + 3][rl] = v.w;
        }
        __syncthreads();
#pragma unroll
        for (int j = 0; j < 4; ++j) {
            const int e  = tid + j * 256;
            const int il = e >> 4;
            const int s4 = e & 15;
            const float g = gq[i0 + il];
            float v0 = tile[il][s4 * 4 + 0] * g;
            float v1 = tile[il][s4 * 4 + 1] * g;
            float v2 = tile[il][s4 * 4 + 2] * g;
            float v3 = tile[il][s4 * 4 + 3] * g;
            ushort4 hh, ll;
            hh.x = f2bf(v0); ll.x = f2bf(v0 - bf2f(hh.x));
            hh.y = f2bf(v1); ll.y = f2bf(v1 - bf2f(hh.y));
            hh.z = f2bf(v2); ll.z = f2bf(v2 - bf2f(hh.z));
            hh.w = f2bf(v3); ll.w = f2bf(v3 - bf2f(hh.w));
            const long o = (long)(i0 + il) * 1024 + c0 + s4 * 4;
            *(ushort4*)(wqT_hi + o) = hh;
            *(ushort4*)(wqT_lo + o) = ll;
        }
    } else if (blk < 4352) {
        const long row = blk - 3328;
        float4 v = ((const float4*)(ctx + row * D_DIM))[tid];
        float ss = v.x*v.x + v.y*v.y + v.z*v.z + v.w*v.w;
#pragma unroll
        for (int m = 32; m; m >>= 1) ss += __shfl_xor(ss, m);
        float* red = &tile[0][0];
        if ((tid & 63) == 0) red[tid >> 6] = ss;
        __syncthreads();
        const float tot = red[0] + red[1] + red[2] + red[3];
        const float scale = rsqrtf(tot * (1.0f / 1024.0f) + 1.1920929e-07f);
        v.x *= scale; v.y *= scale; v.z *= scale; v.w *= scale;
        ushort4 h, l;
        h.x = f2bf(v.x); l.x = f2bf(v.x - bf2f(h.x));
        h.y = f2bf(v.y); l.y = f2bf(v.y - bf2f(h.y));
        h.z = f2bf(v.z); l.z = f2bf(v.z - bf2f(h.z));
        h.w = f2bf(v.w); l.w = f2bf(v.w - bf2f(h.w));
        *(ushort4*)(ch + row * D_DIM + tid * 4) = h;
        *(ushort4*)(cl + row * D_DIM + tid * 4) = l;
    } else {
        const int b = blk - 4352;
        const int p = tid;
        const int* ci = cidx + (b << 12);
        int l = 0, r = 4096;
        while (l < r) { int m = (l + r) >> 1; if (ci[m] < p - 1) l = m + 1; else r = m; }
        const int lo = l;
        r = 4096;
        while (l < r) { int m = (l + r) >> 1; if (ci[m] <= p + 1) l = m + 1; else r = m; }
        bounds[(b << 8) + p] = make_int2(lo, l);
    }
}

// ---------------------------------------------------------------------------
// gemm_kv: z=0: k split-precision -> kh/kl bf16. z=1: v ~= ch@Wv'_hi^T -> f32.
// ---------------------------------------------------------------------------
__global__ __launch_bounds__(256)
void gemm_kv(const unsigned short* __restrict__ ch, const unsigned short* __restrict__ cl,
             const unsigned short* __restrict__ wkh, const unsigned short* __restrict__ wkl,
             const unsigned short* __restrict__ wvh,
             unsigned short* __restrict__ kh, unsigned short* __restrict__ kl,
             float* __restrict__ v_f)
{
    __shared__ unsigned short Ah[4096], Al[4096], Bh[4096], Bl[4096];
    const bool full = (blockIdx.z == 0);
    const unsigned short* Bhp = full ? wkh : wvh;
    const unsigned short* Blp = wkl;

    const int tid = threadIdx.x, lane = tid & 63, wave = tid >> 6;
    const int wm = wave >> 1, wn = wave & 1;
    const long Arow0 = (long)blockIdx.y * 128;
    const int  Brow0 = blockIdx.x * 128;
    const int fr = lane & 15, ks = lane >> 4;
    const int ksz = (ks ^ ((fr >> 1) & 3)) << 4;
    const int kq  = ((tid & 3) ^ ((tid >> 3) & 3)) * 8;
    const int srow = tid >> 2;

    const long a_off0 = (Arow0 + srow) * D_DIM + kq;
    const long a_off1 = (Arow0 + srow + 64) * D_DIM + kq;
    const long b_off0 = (long)(Brow0 + srow) * D_DIM + kq;
    const long b_off1 = (long)(Brow0 + srow + 64) * D_DIM + kq;

    f32x4 acc[4][4] = {};
    char* AhB = (char*)Ah; char* AlB = (char*)Al;
    char* BhB = (char*)Bh; char* BlB = (char*)Bl;

    for (int kt = 0; kt < 32; ++kt) {
        const int k0 = kt * 32;
        gload16(ch + a_off0 + k0, AhB + tid * 16);
        gload16(ch + a_off1 + k0, AhB + 4096 + tid * 16);
        gload16(Bhp + b_off0 + k0, BhB + tid * 16);
        gload16(Bhp + b_off1 + k0, BhB + 4096 + tid * 16);
        if (full) {
            gload16(cl + a_off0 + k0, AlB + tid * 16);
            gload16(cl + a_off1 + k0, AlB + 4096 + tid * 16);
            gload16(Blp + b_off0 + k0, BlB + tid * 16);
            gload16(Blp + b_off1 + k0, BlB + 4096 + tid * 16);
        }
        __syncthreads();

        short8 ah[4], al[4], bh[4], bl[4];
#pragma unroll
        for (int mi = 0; mi < 4; ++mi) {
            const int aoff = (wm * 64 + mi * 16 + fr) * 64 + ksz;
            ah[mi] = *(const short8*)(AhB + aoff);
            if (full) al[mi] = *(const short8*)(AlB + aoff);
        }
#pragma unroll
        for (int ni = 0; ni < 4; ++ni) {
            const int boff = (wn * 64 + ni * 16 + fr) * 64 + ksz;
            bh[ni] = *(const short8*)(BhB + boff);
            if (full) bl[ni] = *(const short8*)(BlB + boff);
        }
#pragma unroll
        for (int mi = 0; mi < 4; ++mi)
#pragma unroll
            for (int ni = 0; ni < 4; ++ni) {
                acc[mi][ni] = __builtin_amdgcn_mfma_f32_16x16x32_bf16(ah[mi], bh[ni], acc[mi][ni], 0, 0, 0);
                if (full) {
                    acc[mi][ni] = __builtin_amdgcn_mfma_f32_16x16x32_bf16(al[mi], bh[ni], acc[mi][ni], 0, 0, 0);
                    acc[mi][ni] = __builtin_amdgcn_mfma_f32_16x16x32_bf16(ah[mi], bl[ni], acc[mi][ni], 0, 0, 0);
                }
            }
        __syncthreads();
    }

    const int c = lane & 15, r0 = (lane >> 4) * 4;
#pragma unroll
    for (int mi = 0; mi < 4; ++mi)
#pragma unroll
        for (int ni = 0; ni < 4; ++ni)
#pragma unroll
            for (int j = 0; j < 4; ++j) {
                const long row = Arow0 + wm * 64 + mi * 16 + r0 + j;
                const int  col = Brow0 + wn * 64 + ni * 16 + c;
                const float val = acc[mi][ni][j];
                if (full) {
                    const unsigned short hh = f2bf(val);
                    kh[row * D_DIM + col] = hh;
                    kl[row * D_DIM + col] = f2bf(val - bf2f(hh));
                } else {
                    v_f[row * D_DIM + col] = val;
                }
            }
}

// ---------------------------------------------------------------------------
// gemm_U: U[b,p,h][i] = sum_d (kh+kl)[(b,p),h*64+d]*(wqT_h+l)[i,h*64+d],
// epilogue -> bf16 hi/lo (Uh/Ul).
// ---------------------------------------------------------------------------
__global__ __launch_bounds__(256)
void gemm_U(const unsigned short* __restrict__ kh, const unsigned short* __restrict__ kl,
            const unsigned short* __restrict__ th, const unsigned short* __restrict__ tl,
            unsigned short* __restrict__ Uh, unsigned short* __restrict__ Ul)
{
    __shared__ unsigned short Ah[4096], Al[4096], Bh[4096], Bl[4096];
    const int h = blockIdx.z;
    const int tid = threadIdx.x, lane = tid & 63, wave = tid >> 6;
    const int wm = wave >> 1, wn = wave & 1;
    const long Arow0 = (long)blockIdx.y * 128;
    const int  Brow0 = blockIdx.x * 128;
    const int fr = lane & 15, ks = lane >> 4;
    const int ksz = (ks ^ ((fr >> 1) & 3)) << 4;
    const int kq  = ((tid & 3) ^ ((tid >> 3) & 3)) * 8;
    const int srow = tid >> 2;
    const int kb = h * 64;

    const long a_off0 = (Arow0 + srow) * D_DIM + kb + kq;
    const long a_off1 = (Arow0 + srow + 64) * D_DIM + kb + kq;
    const long b_off0 = (long)(Brow0 + srow) * D_DIM + kb + kq;
    const long b_off1 = (long)(Brow0 + srow + 64) * D_DIM + kb + kq;

    f32x4 acc[4][4] = {};
    char* AhB = (char*)Ah; char* AlB = (char*)Al;
    char* BhB = (char*)Bh; char* BlB = (char*)Bl;

    for (int kt = 0; kt < 2; ++kt) {
        const int k0 = kt * 32;
        gload16(kh + a_off0 + k0, AhB + tid * 16);
        gload16(kh + a_off1 + k0, AhB + 4096 + tid * 16);
        gload16(kl + a_off0 + k0, AlB + tid * 16);
        gload16(kl + a_off1 + k0, AlB + 4096 + tid * 16);
        gload16(th + b_off0 + k0, BhB + tid * 16);
        gload16(th + b_off1 + k0, BhB + 4096 + tid * 16);
        gload16(tl + b_off0 + k0, BlB + tid * 16);
        gload16(tl + b_off1 + k0, BlB + 4096 + tid * 16);
        __syncthreads();

        short8 ah[4], al[4], bh[4], bl[4];
#pragma unroll
        for (int mi = 0; mi < 4; ++mi) {
            const int aoff = (wm * 64 + mi * 16 + fr) * 64 + ksz;
            ah[mi] = *(const short8*)(AhB + aoff);
            al[mi] = *(const short8*)(AlB + aoff);
        }
#pragma unroll
        for (int ni = 0; ni < 4; ++ni) {
            const int boff = (wn * 64 + ni * 16 + fr) * 64 + ksz;
            bh[ni] = *(const short8*)(BhB + boff);
            bl[ni] = *(const short8*)(BlB + boff);
        }
#pragma unroll
        for (int mi = 0; mi < 4; ++mi)
#pragma unroll
            for (int ni = 0; ni < 4; ++ni) {
                acc[mi][ni] = __builtin_amdgcn_mfma_f32_16x16x32_bf16(ah[mi], bh[ni], acc[mi][ni], 0, 0, 0);
                acc[mi][ni] = __builtin_amdgcn_mfma_f32_16x16x32_bf16(al[mi], bh[ni], acc[mi][ni], 0, 0, 0);
                acc[mi][ni] = __builtin_amdgcn_mfma_f32_16x16x32_bf16(ah[mi], bl[ni], acc[mi][ni], 0, 0, 0);
            }
        __syncthreads();
    }

    const int c = lane & 15, r0 = (lane >> 4) * 4;
#pragma unroll
    for (int mi = 0; mi < 4; ++mi)
#pragma unroll
        for (int ni = 0; ni < 4; ++ni)
#pragma unroll
            for (int j = 0; j < 4; ++j) {
                const long row = Arow0 + wm * 64 + mi * 16 + r0 + j;
                const int  col = Brow0 + wn * 64 + ni * 16 + c;
                const float val = acc[mi][ni][j];
                const long o = ((long)row * 16 + h) * 1024 + col;
                const unsigned short hh = f2bf(val);
                Uh[o] = hh;
                Ul[o] = f2bf(val - bf2f(hh));
            }
}

// ---------------------------------------------------------------------------
// score v7 (r18/r19-validated): 2-way K-split + precomputed bounds.
// ---------------------------------------------------------------------------
__global__ __launch_bounds__(256)
void score_gemm(const float* __restrict__ x, const int* __restrict__ cidx,
                const int2* __restrict__ bounds,
                const unsigned short* __restrict__ Uh, const unsigned short* __restrict__ Ul,
                float* __restrict__ sbuf, float* __restrict__ ssbuf)
{
    const int pg = blockIdx.x;
    const int mh = blockIdx.y;
    const int bz = blockIdx.z;
    const int b  = bz & 3;
    const int ksp = bz >> 2;
    const int kbase = ksp << 9;
    const int p0 = pg * 4;
    const int lo = bounds[(b << 8) + p0].x;
    const int hi = bounds[(b << 8) + p0 + 3].y;
    if (lo + mh * 64 >= hi) return;
    const int* ci = cidx + (b << 12);

    float* const sb = sbuf + (long)ksp * 786432;
    float* const ssb = ssbuf + (ksp << 14);

    __shared__ unsigned short AhS[2][2048], AlS[2][2048];
    __shared__ unsigned short UhS[2][2048], UlS[2][2048];

    const int tid = threadIdx.x, lane = tid & 63, wave = tid >> 6;
    const int fr = lane & 15;
    const int ks = lane >> 4;
    const int ksz = (ks ^ ((fr >> 1) & 3)) << 4;

    const int arow = tid >> 2, aq = tid & 3;
    const int aslot = aq ^ ((arow >> 1) & 3);
    const unsigned short* const Uhb = Uh + ((long)((b << 8) + p0) * 16) * 1024 + kbase;
    const unsigned short* const Ulb = Ul + ((long)((b << 8) + p0) * 16) * 1024 + kbase;
    const float* const xb = x + ((long)b << 12) * 1024 + kbase;

    for (int t0 = lo + mh * 64; t0 < hi; t0 += 128) {
        const int tc0 = (t0 + arow < hi) ? (t0 + arow) : (hi - 1);
        const float* xr = xb + (long)tc0 * 1024 + aq * 8;
        float ss = 0.f;

        gload16(Uhb + (long)arow * 1024 + aslot * 8, (char*)&UhS[0][0] + tid * 16);
        gload16(Ulb + (long)arow * 1024 + aslot * 8, (char*)&UlS[0][0] + tid * 16);
        {
            const float4 v0 = *(const float4*)(xr);
            const float4 v1 = *(const float4*)(xr + 4);
            ss += v0.x*v0.x + v0.y*v0.y + v0.z*v0.z + v0.w*v0.w
                + v1.x*v1.x + v1.y*v1.y + v1.z*v1.z + v1.w*v1.w;
            short8 hv, lv;
            unsigned short h_;
            h_ = f2bf(v0.x); hv[0] = (short)h_; lv[0] = (short)f2bf(v0.x - bf2f(h_));
            h_ = f2bf(v0.y); hv[1] = (short)h_; lv[1] = (short)f2bf(v0.y - bf2f(h_));
            h_ = f2bf(v0.z); hv[2] = (short)h_; lv[2] = (short)f2bf(v0.z - bf2f(h_));
            h_ = f2bf(v0.w); hv[3] = (short)h_; lv[3] = (short)f2bf(v0.w - bf2f(h_));
            h_ = f2bf(v1.x); hv[4] = (short)h_; lv[4] = (short)f2bf(v1.x - bf2f(h_));
            h_ = f2bf(v1.y); hv[5] = (short)h_; lv[5] = (short)f2bf(v1.y - bf2f(h_));
            h_ = f2bf(v1.z); hv[6] = (short)h_; lv[6] = (short)f2bf(v1.z - bf2f(h_));
            h_ = f2bf(v1.w); hv[7] = (short)h_; lv[7] = (short)f2bf(v1.w - bf2f(h_));
            *(short8*)((char*)&AhS[0][0] + arow * 64 + aslot * 16) = hv;
            *(short8*)((char*)&AlS[0][0] + arow * 64 + aslot * 16) = lv;
        }
        __syncthreads();

        f32x4 acc[4] = {};
        for (int t = 0; t < 16; ++t) {
            const int cur = t & 1, nxt = cur ^ 1;
            float4 v0, v1;
            if (t < 15) {
                const int k0n = (t + 1) * 32;
                gload16(Uhb + (long)arow * 1024 + k0n + aslot * 8, (char*)&UhS[nxt][0] + tid * 16);
                gload16(Ulb + (long)arow * 1024 + k0n + aslot * 8, (char*)&UlS[nxt][0] + tid * 16);
                v0 = *(const float4*)(xr + k0n);
                v1 = *(const float4*)(xr + k0n + 4);
            }

            const int aoff = cur * 4096 + (wave * 16 + fr) * 64 + ksz;
            const short8 ah = *(const short8*)((char*)&AhS[0][0] + aoff);
            const short8 al = *(const short8*)((char*)&AlS[0][0] + aoff);
#pragma unroll
            for (int ni = 0; ni < 4; ++ni) {
                const int boff = cur * 4096 + (ni * 16 + fr) * 64 + ksz;
                const short8 uh = *(const short8*)((char*)&UhS[0][0] + boff);
                const short8 ul = *(const short8*)((char*)&UlS[0][0] + boff);
                acc[ni] = __builtin_amdgcn_mfma_f32_16x16x32_bf16(ah, uh, acc[ni], 0, 0, 0);
                acc[ni] = __builtin_amdgcn_mfma_f32_16x16x32_bf16(al, uh, acc[ni], 0, 0, 0);
                acc[ni] = __builtin_amdgcn_mfma_f32_16x16x32_bf16(ah, ul, acc[ni], 0, 0, 0);
            }

            if (t < 15) {
                ss += v0.x*v0.x + v0.y*v0.y + v0.z*v0.z + v0.w*v0.w
                    + v1.x*v1.x + v1.y*v1.y + v1.z*v1.z + v1.w*v1.w;
                short8 hv, lv;
                unsigned short h_;
                h_ = f2bf(v0.x); hv[0] = (short)h_; lv[0] = (short)f2bf(v0.x - bf2f(h_));
                h_ = f2bf(v0.y); hv[1] = (short)h_; lv[1] = (short)f2bf(v0.y - bf2f(h_));
                h_ = f2bf(v0.z); hv[2] = (short)h_; lv[2] = (short)f2bf(v0.z - bf2f(h_));
                h_ = f2bf(v0.w); hv[3] = (short)h_; lv[3] = (short)f2bf(v0.w - bf2f(h_));
                h_ = f2bf(v1.x); hv[4] = (short)h_; lv[4] = (short)f2bf(v1.x - bf2f(h_));
                h_ = f2bf(v1.y); hv[5] = (short)h_; lv[5] = (short)f2bf(v1.y - bf2f(h_));
                h_ = f2bf(v1.z); hv[6] = (short)h_; lv[6] = (short)f2bf(v1.z - bf2f(h_));
                h_ = f2bf(v1.w); hv[7] = (short)h_; lv[7] = (short)f2bf(v1.w - bf2f(h_));
                *(short8*)((char*)&AhS[0][0] + nxt * 4096 + arow * 64 + aslot * 16) = hv;
                *(short8*)((char*)&AlS[0][0] + nxt * 4096 + arow * 64 + aslot * 16) = lv;
            }
            __syncthreads();
        }

        ss += __shfl_xor(ss, 1);
        ss += __shfl_xor(ss, 2);
        if (aq == 0 && t0 + arow < hi)
            ssb[(b << 12) + t0 + arow] = ss;

        const int hcol = lane & 15;
        const int r0j = (lane >> 4) * 4;
#pragma unroll
        for (int j = 0; j < 4; ++j) {
            const int trow = t0 + wave * 16 + r0j + j;
            if (trow < hi) {
                const long tg = ((long)b << 12) + trow;
                const int idx = ci[trow];
#pragma unroll
                for (int ni = 0; ni < 4; ++ni) {
                    const int dp = p0 + ni - idx + 1;
                    if (dp >= 0 && dp <= 2)
                        sb[(tg * 16 + hcol) * 3 + dp] = acc[ni][j];
                }
            }
        }
        __syncthreads();
    }
}

// ---------------------------------------------------------------------------
// attnout: dot = sum of K-halves; s = dot*rsqrt(mean xx+eps)/8; w=relu(s)^2,
// normalize, out = sum w*v. ao bf16.
// ---------------------------------------------------------------------------
__global__ __launch_bounds__(256)
void attnout_kernel(const float* __restrict__ sbuf, const float* __restrict__ ssbuf,
                    const float* __restrict__ vf, const int* __restrict__ cidx,
                    unsigned short* __restrict__ ao)
{
    const int tid = threadIdx.x;
    const int tg = tid >> 4, h = tid & 15;
    const int t = blockIdx.x * 16 + tg;
    const int b = t >> 12;
    const int idx = cidx[t];
    const float* sb0 = sbuf + ((long)t * 16 + h) * 3;
    const float* sb1 = sb0 + 786432;
    const float ssum = ssbuf[t] + ssbuf[t + 16384];
    const float scale = rsqrtf(ssum * (1.0f / 1024.0f) + 1.1920929e-07f) * 0.125f;
    float w0 = 0.f, w1 = 0.f, w2 = 0.f, wsum = 0.f;
    if (idx - 1 >= 0) { float s = (sb0[0] + sb1[0]) * scale; if (s > 0.f) { w0 = s * s; wsum += w0; } }
    { float s = (sb0[1] + sb1[1]) * scale; if (s > 0.f) { w1 = s * s; wsum += w1; } }
    if (idx + 1 < 256) { float s = (sb0[2] + sb1[2]) * scale; if (s > 0.f) { w2 = s * s; wsum += w2; } }
    const float inv = 1.0f / fmaxf(wsum, 1e-6f);
    w0 *= inv; w1 *= inv; w2 *= inv;
    const int p0 = idx > 0 ? idx - 1 : 0;
    const int p2 = idx < 255 ? idx + 1 : 255;
    const float4* v0 = (const float4*)(vf + ((long)(b * 256 + p0)) * 1024 + h * 64);
    const float4* v1 = (const float4*)(vf + ((long)(b * 256 + idx)) * 1024 + h * 64);
    const float4* v2 = (const float4*)(vf + ((long)(b * 256 + p2)) * 1024 + h * 64);
    ushort4* aop = (ushort4*)(ao + (long)t * 1024 + h * 64);
#pragma unroll
    for (int q = 0; q < 16; ++q) {
        float4 a0 = v0[q], a1 = v1[q], a2 = v2[q];
        ushort4 o;
        o.x = f2bf(w0 * a0.x + w1 * a1.x + w2 * a2.x);
        o.y = f2bf(w0 * a0.y + w1 * a1.y + w2 * a2.y);
        o.z = f2bf(w0 * a0.z + w1 * a1.z + w2 * a2.z);
        o.w = f2bf(w0 * a0.w + w1 * a1.w + w2 * a2.w);
        aop[q] = o;
    }
}

// ---------------------------------------------------------------------------
// out = x + ao @ Wo^T, 256x256, swizzled, 8-PHASE deep-pipelined (r15/r19).
// ---------------------------------------------------------------------------
__global__ __launch_bounds__(512, 2)
void gemm_out256(const unsigned short* __restrict__ A,
                 const unsigned short* __restrict__ W,
                 float* __restrict__ C, const float* __restrict__ resid)
{
    __shared__ unsigned short As[4][8192];
    __shared__ unsigned short Bs[4][8192];

    const int lin = blockIdx.x;
    const int bx = (lin >> 3) & 3;
    const int by = ((lin >> 5) << 3) | (lin & 7);
    const long row0 = (long)by * 256;
    const int  col0 = bx * 256;

    const int tid = threadIdx.x, lane = tid & 63, wave = tid >> 6;
    const int wm = wave >> 2, wn = wave & 3;
    const int fr = lane & 15, ks = lane >> 4;
    const int ksz = (ks ^ ((fr >> 1) & 3)) << 4;
    const int kq  = ((tid & 3) ^ ((tid >> 3) & 3)) * 8;
    const int srow = tid >> 2;

    const long a_off0 = (row0 + srow) * D_DIM + kq;
    const long a_off1 = (row0 + 128 + srow) * D_DIM + kq;
    const long b_off0 = (long)(col0 + srow) * D_DIM + kq;
    const long b_off1 = (long)(col0 + 128 + srow) * D_DIM + kq;

    f32x4 acc[8][4] = {};

#define STAGE_A(X) do { const int kofs_ = (X) * 32;                          \
    char* base_ = (char*)&As[(X) & 3][0];                                    \
    gload16(A + a_off0 + kofs_, base_ + tid * 16);                           \
    gload16(A + a_off1 + kofs_, base_ + 8192 + tid * 16); } while (0)
#define STAGE_B(X) do { const int kofs_ = (X) * 32;                          \
    char* base_ = (char*)&Bs[(X) & 3][0];                                    \
    gload16(W + b_off0 + kofs_, base_ + tid * 16);                           \
    gload16(W + b_off1 + kofs_, base_ + 8192 + tid * 16); } while (0)

    STAGE_A(0); STAGE_B(0); STAGE_A(1); STAGE_B(1); STAGE_A(2); STAGE_B(2);
    asm volatile("s_waitcnt vmcnt(4)" ::: "memory");
    __builtin_amdgcn_s_barrier();
    __builtin_amdgcn_sched_barrier(0);

    short8 bfrag[4];

    for (int i = 0; i < 8; ++i) {
        const int Tb = i * 4;
        const bool last = (i == 7);
#pragma unroll
        for (int ph = 0; ph < 8; ++ph) {
            const int tp = ph >> 1;
            const int h  = ph & 1;
            const int rg = tp;
            if (h == 0) {
#pragma unroll
                for (int ni = 0; ni < 4; ++ni)
                    bfrag[ni] = *(const short8*)((char*)&Bs[rg][0] +
                                (wn * 64 + ni * 16 + fr) * 64 + ksz);
            }
            short8 afrag[4];
#pragma unroll
            for (int mi = 0; mi < 4; ++mi)
                afrag[mi] = *(const short8*)((char*)&As[rg][0] +
                            (wm * 128 + h * 64 + mi * 16 + fr) * 64 + ksz);
            {
                const int SX = Tb + 3 + tp;
                if (SX < 32) {
                    if (h == 0) STAGE_A(SX); else STAGE_B(SX);
                }
            }
            if (ph == 3) {
                if (last) asm volatile("s_waitcnt vmcnt(0)" ::: "memory");
                else      asm volatile("s_waitcnt vmcnt(4)" ::: "memory");
            } else if (ph == 7) {
                if (!last) asm volatile("s_waitcnt vmcnt(4)" ::: "memory");
            }
            __builtin_amdgcn_s_barrier();
            asm volatile("s_waitcnt lgkmcnt(0)" ::: "memory");
            __builtin_amdgcn_sched_barrier(0);
            __builtin_amdgcn_s_setprio(1);
#pragma unroll
            for (int mi = 0; mi < 4; ++mi)
#pragma unroll
                for (int ni = 0; ni < 4; ++ni)
                    acc[h * 4 + mi][ni] = __builtin_amdgcn_mfma_f32_16x16x32_bf16(
                        afrag[mi], bfrag[ni], acc[h * 4 + mi][ni], 0, 0, 0);
            __builtin_amdgcn_s_setprio(0);
            __builtin_amdgcn_sched_barrier(0);
            __builtin_amdgcn_s_barrier();
            __builtin_amdgcn_sched_barrier(0);
        }
    }
#undef STAGE_A
#undef STAGE_B

    const int c = lane & 15, rg2 = lane >> 4;
#pragma unroll
    for (int mi = 0; mi < 8; ++mi)
#pragma unroll
        for (int ni = 0; ni < 4; ++ni)
#pragma unroll
            for (int j = 0; j < 4; ++j) {
                const long row = row0 + wm * 128 + mi * 16 + rg2 * 4 + j;
                const int  col = col0 + wn * 64 + ni * 16 + c;
                C[row * D_DIM + col] = resid[row * D_DIM + col] + acc[mi][ni][j];
            }
}

// ---------------------------------------------------------------------------
extern "C" void kernel_launch(void* const* d_in, const int* in_sizes, int n_in,
                              void* d_out, int out_size, void* d_ws, size_t ws_size,
                              hipStream_t stream)
{
    const float* x    = (const float*)d_in[0];
    const float* ctx  = (const float*)d_in[1];
    const int*   cidx = (const int*)d_in[2];
    const float* gq   = (const float*)d_in[3];
    const float* gkv  = (const float*)d_in[4];
    const float* Wq   = (const float*)d_in[5];
    const float* Wk   = (const float*)d_in[6];
    const float* Wv   = (const float*)d_in[7];
    const float* Wo   = (const float*)d_in[8];
    float* out = (float*)d_out;

    char* ws = (char*)d_ws;
    const size_t MB = 1 << 20;
    unsigned short* wqT_hi = (unsigned short*)(ws + 0 * MB);
    unsigned short* wqT_lo = (unsigned short*)(ws + 2 * MB);
    unsigned short* wk_hi  = (unsigned short*)(ws + 4 * MB);
    unsigned short* wk_lo  = (unsigned short*)(ws + 6 * MB);
    unsigned short* wv_hi  = (unsigned short*)(ws + 8 * MB);
    unsigned short* wv_lo  = (unsigned short*)(ws + 10 * MB);
    unsigned short* wo_b   = (unsigned short*)(ws + 12 * MB);
    unsigned short* ch = (unsigned short*)(ws + 14 * MB);
    unsigned short* cl = (unsigned short*)(ws + 16 * MB);
    unsigned short* kh = (unsigned short*)(ws + 18 * MB);
    unsigned short* kl = (unsigned short*)(ws + 20 * MB);
    float* v_f = (float*)(ws + 22 * MB);                      // 4MB
    unsigned short* Uh = (unsigned short*)(ws + 26 * MB);     // 32MB (26..58)
    unsigned short* Ul = (unsigned short*)(ws + 58 * MB);     // 32MB (58..90)
    unsigned short* ao_b = (unsigned short*)(ws + 26 * MB);   // 32MB, ALIASES Uh
        // (Uh dead after score_gemm; attnout writes ao afterwards)
    float* sbuf  = (float*)(ws + 91 * MB);                    // 2 x 3MB (91..97)
    float* ssbuf = (float*)(ws + 97 * MB);                    // 2 x 64KB
    int2*  bounds = (int2*)(ws + 98 * MB);                    // 8KB; total ~98MB

    // 1. fused preprocessing: convw | transq | rms_split(ctx) | bounds
    prep_kernel<<<4356, 256, 0, stream>>>(Wk, Wv, Wo, Wq, gkv, gq, ctx, cidx,
                                          wk_hi, wk_lo, wv_hi, wv_lo, wo_b,
                                          wqT_hi, wqT_lo, ch, cl, bounds);
    // 2. k (split bf16), v (f32)
    gemm_kv<<<dim3(8, 8, 2), 256, 0, stream>>>(ch, cl, wk_hi, wk_lo, wv_hi,
                                               kh, kl, v_f);
    // 3. U = per-head Wq'^T k, bf16 hi/lo
    gemm_U<<<dim3(8, 8, 16), 256, 0, stream>>>(kh, kl, wqT_hi, wqT_lo, Uh, Ul);
    // 4. band scores (2-way K-split, precomputed bounds)
    score_gemm<<<dim3(64, 2, 8), 256, 0, stream>>>(x, cidx, bounds, Uh, Ul,
                                                   sbuf, ssbuf);
    // 5. normalize + weighted V -> ao
    attnout_kernel<<<1024, 256, 0, stream>>>(sbuf, ssbuf, v_f, cidx, ao_b);
    // 6. out = x + ao @ Wo^T (256x256 8-phase)
    gemm_out256<<<256, 512, 0, stream>>>(ao_b, wo_b, out, x);
}